// Round 3
// baseline (1369.067 us; speedup 1.0000x reference)
//
#include <hip/hip_runtime.h>
#include <math.h>

#define N_TOK 8192
#define C_DIM 1024
#define NEXP 8
#define CAP 2560
#define NASSIGN (2 * N_TOK)
#define ROW_F4 (NEXP * CAP / 4)  /* 5120 float4 per token-row of cb or mask */

// ---------------------------------------------------------------------------
// Kernel 1: gating — logits = x @ w_g^T, top-2, softmax over the top-2.
// One wave (64 lanes) per token. w_g (32 KB) staged in LDS as float4.
// fp64 accumulation so the expert ranking matches the reference even near
// ties.
// ---------------------------------------------------------------------------
__global__ __launch_bounds__(256) void gate_kernel(const float* __restrict__ x,
                                                   const float* __restrict__ wg,
                                                   int* __restrict__ epair,
                                                   float* __restrict__ p1o,
                                                   float* __restrict__ p2o) {
    __shared__ float4 wls[NEXP * 256];  // 32 KB
    const int tid = threadIdx.x;
    const float4* wg4 = (const float4*)wg;
    for (int i = tid; i < NEXP * 256; i += 256) wls[i] = wg4[i];
    __syncthreads();

    const int wave = tid >> 6;
    const int lane = tid & 63;
    const int n = blockIdx.x * 4 + wave;
    const float4* x4 = (const float4*)(x + (size_t)n * C_DIM);

    double acc[NEXP];
#pragma unroll
    for (int e = 0; e < NEXP; ++e) acc[e] = 0.0;

#pragma unroll
    for (int c = 0; c < 4; ++c) {
        float4 xv = x4[c * 64 + lane];
#pragma unroll
        for (int e = 0; e < NEXP; ++e) {
            float4 wv = wls[e * 256 + c * 64 + lane];
            acc[e] = fma((double)xv.x, (double)wv.x, acc[e]);
            acc[e] = fma((double)xv.y, (double)wv.y, acc[e]);
            acc[e] = fma((double)xv.z, (double)wv.z, acc[e]);
            acc[e] = fma((double)xv.w, (double)wv.w, acc[e]);
        }
    }

    // wave-64 butterfly reduction of the 8 accumulators
#pragma unroll
    for (int off = 32; off >= 1; off >>= 1) {
#pragma unroll
        for (int e = 0; e < NEXP; ++e) acc[e] += __shfl_xor(acc[e], off);
    }

    if (lane == 0) {
        // top-2 with jax.lax.top_k tie-break (lower index first)
        double v1 = -1e300, v2 = -1e300;
        int i1 = 0, i2 = 0;
#pragma unroll
        for (int e = 0; e < NEXP; ++e) {
            double v = acc[e];
            if (v > v1) { v2 = v1; i2 = i1; v1 = v; i1 = e; }
            else if (v > v2) { v2 = v; i2 = e; }
        }
        double z = exp(v2 - v1);          // <= 1
        double inv = 1.0 / (1.0 + z);
        epair[n] = i1 | (i2 << 8);
        p1o[n] = (float)inv;
        p2o[n] = (float)(z * inv);
    }
}

// ---------------------------------------------------------------------------
// Kernel 2: priority-ordered rank via prefix count. Assignment order is
// k-major (all 1st choices for n=0..N-1, then all 2nd choices). 8 experts
// packed as 16-bit fields into two u64s; single-block Hillis-Steele scan.
// Also emits used_capacity[e] = min(total[e], CAP) as float.
// ---------------------------------------------------------------------------
__global__ __launch_bounds__(1024) void scan_kernel(const int* __restrict__ epair,
                                                    int* __restrict__ rank,
                                                    float* __restrict__ used_cap) {
    __shared__ unsigned long long slo[1024];
    __shared__ unsigned long long shi[1024];
    const int t = threadIdx.x;

    int evals[16];
    unsigned long long lo = 0, hi = 0;
#pragma unroll
    for (int j = 0; j < 16; ++j) {
        int i = t * 16 + j;
        int n = i & (N_TOK - 1);
        int pr = epair[n];
        int e = (i >= N_TOK) ? ((pr >> 8) & 0xff) : (pr & 0xff);
        evals[j] = e;
        unsigned long long inc = 1ULL << (16 * (e & 3));
        if (e < 4) lo += inc; else hi += inc;
    }
    slo[t] = lo;
    shi[t] = hi;
    __syncthreads();

    for (int d = 1; d < 1024; d <<= 1) {
        unsigned long long alo = 0, ahi = 0;
        if (t >= d) { alo = slo[t - d]; ahi = shi[t - d]; }
        __syncthreads();
        if (t >= d) { slo[t] += alo; shi[t] += ahi; }
        __syncthreads();
    }

    unsigned long long rlo = (t > 0) ? slo[t - 1] : 0ULL;
    unsigned long long rhi = (t > 0) ? shi[t - 1] : 0ULL;
#pragma unroll
    for (int j = 0; j < 16; ++j) {
        int e = evals[j];
        int sh = 16 * (e & 3);
        int r = (int)(((e < 4 ? rlo : rhi) >> sh) & 0xffff);
        rank[t * 16 + j] = r;
        if (e < 4) rlo += 1ULL << sh; else rhi += 1ULL << sh;
    }

    if (t == 1023) {
        unsigned long long tlo = slo[1023], thi = shi[1023];
#pragma unroll
        for (int e = 0; e < NEXP; ++e) {
            int c = (int)(((e < 4 ? tlo : thi) >> (16 * (e & 3))) & 0xffff);
            used_cap[e] = (float)(c < CAP ? c : CAP);
        }
    }
}

// ---------------------------------------------------------------------------
// Kernel 3: value-computing flat fill. One float4-pair (cb + mask) per
// thread, perfectly linear store stream per array — memset-like pattern,
// but the value is computed inline so no separate scatter pass, no RMW,
// no memset dispatch, no race (every element written exactly once).
// Per-token scalars are blockIdx.y-uniform -> scalar loads, L1/L2-served
// (~160 KB total reads vs 1.34 GB writes).
// grid = (ROW_F4/256, N_TOK) = (20, 8192).
// ---------------------------------------------------------------------------
__global__ __launch_bounds__(256) void out_kernel(const int* __restrict__ epair,
                                                  const float* __restrict__ p1,
                                                  const float* __restrict__ p2,
                                                  const int* __restrict__ rank,
                                                  float* __restrict__ cb,
                                                  float* __restrict__ mask) {
    const int n = blockIdx.y;
    const int i = blockIdx.x * 256 + threadIdx.x;   // float4 index within row, [0, 5120)
    const int e = i / 640;                           // expert of this float4 (CAP/4 = 640)
    const int c0 = (i - e * 640) * 4;                // first capacity slot covered

    const int pr = epair[n];
    const int e1 = pr & 0xff;
    const int e2 = (pr >> 8) & 0xff;
    const int r1 = rank[n];
    const int r2 = rank[N_TOK + n];
    const float pv1 = p1[n];
    const float pv2 = p2[n];

    // slot matches: r < CAP is implied by r == c (c < 2560 always);
    // e1 != e2 (top-2 distinct), so at most one match per component.
    float4 cbv = make_float4(0.f, 0.f, 0.f, 0.f);
    float4 mkv = make_float4(0.f, 0.f, 0.f, 0.f);
    const bool a1 = (e == e1), a2 = (e == e2);
    if (a1 | a2) {  // uniform-ish branch: only 2 of 8 expert-stripes enter
#pragma unroll
        for (int j = 0; j < 4; ++j) {
            const int c = c0 + j;
            const bool m1 = a1 && (r1 == c);
            const bool m2 = a2 && (r2 == c);
            const float cv = m1 ? pv1 : (m2 ? pv2 : 0.f);
            const float mv = (m1 | m2) ? 1.f : 0.f;
            if (j == 0) { cbv.x = cv; mkv.x = mv; }
            if (j == 1) { cbv.y = cv; mkv.y = mv; }
            if (j == 2) { cbv.z = cv; mkv.z = mv; }
            if (j == 3) { cbv.w = cv; mkv.w = mv; }
        }
    }

    const size_t base = (size_t)n * ROW_F4 + i;
    ((float4*)cb)[base] = cbv;
    ((float4*)mask)[base] = mkv;
}

extern "C" void kernel_launch(void* const* d_in, const int* in_sizes, int n_in,
                              void* d_out, int out_size, void* d_ws, size_t ws_size,
                              hipStream_t stream) {
    const float* x  = (const float*)d_in[0];
    const float* wg = (const float*)d_in[1];

    float* out  = (float*)d_out;
    float* used = out;                                    // [8]
    float* cb   = out + NEXP;                             // [N, E, CAP]
    float* mask = cb + (size_t)N_TOK * NEXP * CAP;        // [N, E, CAP]

    int*   epair = (int*)d_ws;                            // [N]
    float* p1    = (float*)d_ws + N_TOK;                  // [N]
    float* p2    = (float*)d_ws + 2 * N_TOK;              // [N]
    int*   rank  = (int*)d_ws + 3 * N_TOK;                // [2N]

    gate_kernel<<<N_TOK / 4, 256, 0, stream>>>(x, wg, epair, p1, p2);
    scan_kernel<<<1, 1024, 0, stream>>>(epair, rank, used);
    out_kernel<<<dim3(ROW_F4 / 256, N_TOK), 256, 0, stream>>>(epair, p1, p2, rank, cb, mask);
}

// Round 4
// 1326.598 us; speedup vs baseline: 1.0320x; 1.0320x over previous
//
#include <hip/hip_runtime.h>
#include <math.h>

#define N_TOK 8192
#define C_DIM 1024
#define NEXP 8
#define CAP 2560
#define NASSIGN (2 * N_TOK)

// ---------------------------------------------------------------------------
// Kernel 1: gating — logits = x @ w_g^T, top-2, softmax over the top-2.
// One wave (64 lanes) per token. w_g (32 KB) staged in LDS as float4.
// fp64 accumulation so the expert ranking matches the reference even near
// ties.
// ---------------------------------------------------------------------------
__global__ __launch_bounds__(256) void gate_kernel(const float* __restrict__ x,
                                                   const float* __restrict__ wg,
                                                   int* __restrict__ epair,
                                                   float* __restrict__ p1o,
                                                   float* __restrict__ p2o) {
    __shared__ float4 wls[NEXP * 256];  // 32 KB
    const int tid = threadIdx.x;
    const float4* wg4 = (const float4*)wg;
    for (int i = tid; i < NEXP * 256; i += 256) wls[i] = wg4[i];
    __syncthreads();

    const int wave = tid >> 6;
    const int lane = tid & 63;
    const int n = blockIdx.x * 4 + wave;
    const float4* x4 = (const float4*)(x + (size_t)n * C_DIM);

    double acc[NEXP];
#pragma unroll
    for (int e = 0; e < NEXP; ++e) acc[e] = 0.0;

#pragma unroll
    for (int c = 0; c < 4; ++c) {
        float4 xv = x4[c * 64 + lane];
#pragma unroll
        for (int e = 0; e < NEXP; ++e) {
            float4 wv = wls[e * 256 + c * 64 + lane];
            acc[e] = fma((double)xv.x, (double)wv.x, acc[e]);
            acc[e] = fma((double)xv.y, (double)wv.y, acc[e]);
            acc[e] = fma((double)xv.z, (double)wv.z, acc[e]);
            acc[e] = fma((double)xv.w, (double)wv.w, acc[e]);
        }
    }

    // wave-64 butterfly reduction of the 8 accumulators
#pragma unroll
    for (int off = 32; off >= 1; off >>= 1) {
#pragma unroll
        for (int e = 0; e < NEXP; ++e) acc[e] += __shfl_xor(acc[e], off);
    }

    if (lane == 0) {
        // top-2 with jax.lax.top_k tie-break (lower index first)
        double v1 = -1e300, v2 = -1e300;
        int i1 = 0, i2 = 0;
#pragma unroll
        for (int e = 0; e < NEXP; ++e) {
            double v = acc[e];
            if (v > v1) { v2 = v1; i2 = i1; v1 = v; i1 = e; }
            else if (v > v2) { v2 = v; i2 = e; }
        }
        double z = exp(v2 - v1);          // <= 1
        double inv = 1.0 / (1.0 + z);
        epair[n] = i1 | (i2 << 8);
        p1o[n] = (float)inv;
        p2o[n] = (float)(z * inv);
    }
}

// ---------------------------------------------------------------------------
// Kernel 2 (scan + fused scatter): priority-ordered rank via prefix count,
// then scatter the kept assignments directly into the memset-zeroed
// cb/mask. Assignment order is k-major (all 1st choices for n=0..N-1, then
// all 2nd choices). 8 experts packed as 16-bit fields into two u64s;
// single-block Hillis-Steele scan. Each thread owns 16 consecutive
// assignments, so after the scan its exclusive running counts ARE the slot
// indices — it writes the <=16 (p, 1.0f) pairs itself. Removes the old
// separate scatter dispatch and the rank[] round-trip.
// Also emits used_capacity[e] = min(total[e], CAP) as float.
// ---------------------------------------------------------------------------
__global__ __launch_bounds__(1024) void scan_scatter_kernel(const int* __restrict__ epair,
                                                            const float* __restrict__ p1,
                                                            const float* __restrict__ p2,
                                                            float* __restrict__ used_cap,
                                                            float* __restrict__ cb,
                                                            float* __restrict__ mask) {
    __shared__ unsigned long long slo[1024];
    __shared__ unsigned long long shi[1024];
    const int t = threadIdx.x;

    int evals[16];
    unsigned long long lo = 0, hi = 0;
#pragma unroll
    for (int j = 0; j < 16; ++j) {
        int i = t * 16 + j;
        int n = i & (N_TOK - 1);
        int pr = epair[n];
        int e = (i >= N_TOK) ? ((pr >> 8) & 0xff) : (pr & 0xff);
        evals[j] = e;
        unsigned long long inc = 1ULL << (16 * (e & 3));
        if (e < 4) lo += inc; else hi += inc;
    }
    slo[t] = lo;
    shi[t] = hi;
    __syncthreads();

    for (int d = 1; d < 1024; d <<= 1) {
        unsigned long long alo = 0, ahi = 0;
        if (t >= d) { alo = slo[t - d]; ahi = shi[t - d]; }
        __syncthreads();
        if (t >= d) { slo[t] += alo; shi[t] += ahi; }
        __syncthreads();
    }

    unsigned long long rlo = (t > 0) ? slo[t - 1] : 0ULL;
    unsigned long long rhi = (t > 0) ? shi[t - 1] : 0ULL;
#pragma unroll
    for (int j = 0; j < 16; ++j) {
        int i = t * 16 + j;
        int n = i & (N_TOK - 1);
        int e = evals[j];
        int sh = 16 * (e & 3);
        int r = (int)(((e < 4 ? rlo : rhi) >> sh) & 0xffff);
        if (e < 4) rlo += 1ULL << sh; else rhi += 1ULL << sh;
        if (r < CAP) {
            float p = (i >= N_TOK) ? p2[n] : p1[n];
            size_t idx = (size_t)n * (NEXP * CAP) + (size_t)e * CAP + (size_t)r;
            cb[idx] = p;
            mask[idx] = 1.0f;
        }
    }

    if (t == 1023) {
        unsigned long long tlo = slo[1023], thi = shi[1023];
#pragma unroll
        for (int e = 0; e < NEXP; ++e) {
            int c = (int)(((e < 4 ? tlo : thi) >> (16 * (e & 3))) & 0xffff);
            used_cap[e] = (float)(c < CAP ? c : CAP);
        }
    }
}

extern "C" void kernel_launch(void* const* d_in, const int* in_sizes, int n_in,
                              void* d_out, int out_size, void* d_ws, size_t ws_size,
                              hipStream_t stream) {
    const float* x  = (const float*)d_in[0];
    const float* wg = (const float*)d_in[1];

    float* out  = (float*)d_out;
    float* used = out;                                    // [8]
    float* cb   = out + NEXP;                             // [N, E, CAP]
    float* mask = cb + (size_t)N_TOK * NEXP * CAP;        // [N, E, CAP]

    int*   epair = (int*)d_ws;                            // [N]
    float* p1    = (float*)d_ws + N_TOK;                  // [N]
    float* p2    = (float*)d_ws + 2 * N_TOK;              // [N]

    // Bulk zero via the runtime fill kernel (measured 6.2 TB/s — both
    // custom fill attempts only reached ~4.7 TB/s). out_size is a float
    // count (established R1: removing this memset saved nothing, so R0's
    // "4x over-write" theory was wrong and this is exactly 1.342 GB).
    hipMemsetAsync(d_out, 0, (size_t)out_size * sizeof(float), stream);

    gate_kernel<<<N_TOK / 4, 256, 0, stream>>>(x, wg, epair, p1, p2);
    scan_scatter_kernel<<<1, 1024, 0, stream>>>(epair, p1, p2, used, cb, mask);
}